// Round 3
// baseline (8799.886 us; speedup 1.0000x reference)
//
#include <hip/hip_runtime.h>
#include <hip/hip_bf16.h>

#define HH 51
#define NT 10            // N tiles of 16 covering 153 (pad to 160)
#define TPB 64           // one wave per block
#define BPB 8            // batch per block

typedef _Float16 half8 __attribute__((ext_vector_type(8)));
typedef float f4 __attribute__((ext_vector_type(4)));

__device__ __forceinline__ float bf2f(unsigned short u) {
    return __uint_as_float(((unsigned)u) << 16);
}
__device__ __forceinline__ float loadf(const void* p, size_t idx, bool isbf) {
    return isbf ? bf2f(((const unsigned short*)p)[idx]) : ((const float*)p)[idx];
}
__device__ __forceinline__ void storef(void* p, size_t idx, float v, bool isbf) {
    if (isbf) ((__hip_bfloat16*)p)[idx] = __float2bfloat16(v);
    else      ((float*)p)[idx] = v;
}

// overflow-proof activations
__device__ __forceinline__ float sigm(float v) {
    float e = __expf(-fabsf(v));
    float s = 1.0f / (1.0f + e);
    return (v >= 0.0f) ? s : 1.0f - s;
}
__device__ __forceinline__ float tanh_fast(float v) {
    float e = __expf(-2.0f * fabsf(v));
    float t = (1.0f - e) / (1.0f + e);
    return (v >= 0.0f) ? t : -t;
}

__device__ __forceinline__ f4 MF(half8 a, half8 b, f4 c) {
    return __builtin_amdgcn_mfma_f32_16x16x32_f16(a, b, c, 0, 0, 0);
}

// LDS layout (union of init staging and runtime buffers):
//   staging: _Float16 ws[3][160][64]                      = 61440 B
//   runtime: f32 gm1[160][20] @0      (12800 B)
//            f32 gm2[160][20] @12800  (12800 B)
//            f16 h1hi[16][72] @25600  (2304 B)   h1lo @27904
//            f16 h2hi[16][72] @30208  (2304 B)   h2lo @32512
#define LDS_BYTES 61440

__global__ __launch_bounds__(TPB, 1) void gru_mfma_kernel(
    const void* __restrict__ xg,
    const void* __restrict__ wih1, const void* __restrict__ whh1,
    const void* __restrict__ bih1, const void* __restrict__ bhh1,
    const void* __restrict__ wih2, const void* __restrict__ whh2,
    const void* __restrict__ bih2, const void* __restrict__ bhh2,
    const void* __restrict__ wlin, const void* __restrict__ blin_p,
    void* __restrict__ dout, int T, int TF)
{
    __shared__ __align__(16) char ldsraw[LDS_BYTES];

    const int tid  = threadIdx.x;
    const int b    = tid & 7;          // batch slot (elementwise layout)
    const int g8   = tid >> 3;         // item stripe base
    const int m    = tid & 15;         // A-operand row (batch; 8..15 zero)
    const int n16  = tid & 15;         // B/C lane col
    const int quad = tid >> 4;
    const int bg   = blockIdx.x * BPB + b;

    // ---- runtime dtype detection (fp32 vs bf16), wave-uniform ----
    bool isbf;
    {
        const unsigned short* u = (const unsigned short*)whh1;
        int ok = 1;
#pragma unroll
        for (int k = 0; k < 16; ++k) {
            unsigned e = (u[2 * k] >> 7) & 0xFF;
            ok &= (e >= 100 && e <= 125) ? 1 : 0;
        }
        isbf = (ok != 0);
    }

    // ---- stage padded weights (f16) into LDS, bias folded at k=52 ----
    {
        _Float16* ws = (_Float16*)ldsraw;
        const void* wm[3] = { whh1, whh2, wih2 };
        for (int e = tid; e < 3 * 160 * 64; e += TPB) {
            int mt = e / 10240, r = e % 10240;
            int g = r / 64, k = r % 64;
            float v = 0.0f;
            if (g < 3 * HH) {
                if (k < HH) v = loadf(wm[mt], (size_t)g * HH + k, isbf);
                else if (k == 52) {
                    if (mt == 0) v = loadf(bhh1, g, isbf) + ((g < 2 * HH) ? loadf(bih1, g, isbf) : 0.0f);
                    else if (mt == 1) v = loadf(bhh2, g, isbf);
                    else v = loadf(bih2, g, isbf);
                }
            }
            ws[e] = (_Float16)v;
        }
    }
    __syncthreads();

    // ---- B fragments resident in VGPRs for the whole run ----
    half8 Bw[3][NT][2];
    {
        const _Float16* ws = (const _Float16*)ldsraw;
#pragma unroll
        for (int mt = 0; mt < 3; ++mt)
#pragma unroll
            for (int tile = 0; tile < NT; ++tile)
#pragma unroll
                for (int ch = 0; ch < 2; ++ch)
                    Bw[mt][tile][ch] = *(const half8*)(ws + ((size_t)(mt * 160 + 16 * tile + n16)) * 64
                                                          + ch * 32 + quad * 8);
    }
    __syncthreads();   // frags snapshotted; safe to overwrite staging region

    float* gm1      = (float*)ldsraw;
    float* gm2      = (float*)(ldsraw + 12800);
    _Float16* h1hi  = (_Float16*)(ldsraw + 25600);
    _Float16* h1lo  = (_Float16*)(ldsraw + 27904);
    _Float16* h2hi  = (_Float16*)(ldsraw + 30208);
    _Float16* h2lo  = (_Float16*)(ldsraw + 32512);

    // zero h buffers (incl. rows 8..15 and K pad), then set bias slot
    for (int e = tid; e < 2304; e += TPB) ((unsigned*)(ldsraw + 25600))[e] = 0u;
    __syncthreads();
    if (tid < BPB) { h1hi[tid * 72 + 52] = (_Float16)1.0f; h2hi[tid * 72 + 52] = (_Float16)1.0f; }

    // per-item elementwise constants (i = g8 + 8s)
    float wr1[7], wz1[7], wn1[7], bn1[7], wlv[7];
#pragma unroll
    for (int s = 0; s < 7; ++s) {
        int i = g8 + 8 * s;
        bool v = (i < HH);
        wr1[s] = v ? loadf(wih1, i, isbf) : 0.0f;
        wz1[s] = v ? loadf(wih1, HH + i, isbf) : 0.0f;
        wn1[s] = v ? loadf(wih1, 2 * HH + i, isbf) : 0.0f;
        bn1[s] = v ? loadf(bih1, 2 * HH + i, isbf) : 0.0f;
        wlv[s] = v ? loadf(wlin, i, isbf) : 0.0f;
    }
    const float blv = loadf(blin_p, 0, isbf);
    __syncthreads();

    float h1prev[7] = {0, 0, 0, 0, 0, 0, 0};
    float h2prev[7] = {0, 0, 0, 0, 0, 0, 0};
    float out_prev = 0.0f;

    for (int t = 0; t < TF; ++t) {
        float xv = (t < T) ? loadf(xg, (size_t)bg * T + t, isbf) : out_prev;

        // ---- phase A: gh1 = h1.Whh1^T -> gm1 ; gh2 = h2.Whh2^T -> gm2 ----
        {
            half8 a0 = *(const half8*)(h1hi + m * 72 + quad * 8);
            half8 a1 = *(const half8*)(h1hi + m * 72 + 32 + quad * 8);
            half8 a2 = *(const half8*)(h1lo + m * 72 + quad * 8);
            half8 a3 = *(const half8*)(h1lo + m * 72 + 32 + quad * 8);
            half8 c0 = *(const half8*)(h2hi + m * 72 + quad * 8);
            half8 c1 = *(const half8*)(h2hi + m * 72 + 32 + quad * 8);
            half8 c2 = *(const half8*)(h2lo + m * 72 + quad * 8);
            half8 c3 = *(const half8*)(h2lo + m * 72 + 32 + quad * 8);
#pragma unroll
            for (int tile = 0; tile < NT; ++tile) {
                f4 acc = {0.f, 0.f, 0.f, 0.f};
                acc = MF(a0, Bw[0][tile][0], acc);
                acc = MF(a1, Bw[0][tile][1], acc);
                acc = MF(a2, Bw[0][tile][0], acc);
                acc = MF(a3, Bw[0][tile][1], acc);
                *(f4*)(gm1 + (16 * tile + n16) * 20 + 4 * quad) = acc;
                f4 ac2 = {0.f, 0.f, 0.f, 0.f};
                ac2 = MF(c0, Bw[1][tile][0], ac2);
                ac2 = MF(c1, Bw[1][tile][1], ac2);
                ac2 = MF(c2, Bw[1][tile][0], ac2);
                ac2 = MF(c3, Bw[1][tile][1], ac2);
                *(f4*)(gm2 + (16 * tile + n16) * 20 + 4 * quad) = ac2;
            }
        }
        __syncthreads();

        // ---- elem1: layer-1 gates + h1 update ----
#pragma unroll
        for (int s = 0; s < 7; ++s) {
            int i = g8 + 8 * s;
            float hr = gm1[i * 20 + b];
            float hz = gm1[(HH + i) * 20 + b];
            float hn = gm1[(2 * HH + i) * 20 + b];
            float r = sigm(fmaf(xv, wr1[s], hr));
            float z = sigm(fmaf(xv, wz1[s], hz));
            float n = tanh_fast(fmaf(xv, wn1[s], bn1[s]) + r * hn);
            float h = n + z * (h1prev[s] - n);
            h1prev[s] = h;
            if (i < HH) {
                _Float16 hi = (_Float16)h;
                h1hi[b * 72 + i] = hi;
                h1lo[b * 72 + i] = (_Float16)(h - (float)hi);
            }
        }
        __syncthreads();

        // ---- phase B: gi2 = h1new.Wih2^T -> gm1 (reuse) ----
        {
            half8 a0 = *(const half8*)(h1hi + m * 72 + quad * 8);
            half8 a1 = *(const half8*)(h1hi + m * 72 + 32 + quad * 8);
            half8 a2 = *(const half8*)(h1lo + m * 72 + quad * 8);
            half8 a3 = *(const half8*)(h1lo + m * 72 + 32 + quad * 8);
#pragma unroll
            for (int tile = 0; tile < NT; ++tile) {
                f4 acc = {0.f, 0.f, 0.f, 0.f};
                acc = MF(a0, Bw[2][tile][0], acc);
                acc = MF(a1, Bw[2][tile][1], acc);
                acc = MF(a2, Bw[2][tile][0], acc);
                acc = MF(a3, Bw[2][tile][1], acc);
                *(f4*)(gm1 + (16 * tile + n16) * 20 + 4 * quad) = acc;
            }
        }
        __syncthreads();

        // ---- elem2: layer-2 gates + h2 update + linear out ----
        float p = 0.0f;
#pragma unroll
        for (int s = 0; s < 7; ++s) {
            int i = g8 + 8 * s;
            float i2r = gm1[i * 20 + b],            h2r = gm2[i * 20 + b];
            float i2z = gm1[(HH + i) * 20 + b],     h2z = gm2[(HH + i) * 20 + b];
            float i2n = gm1[(2 * HH + i) * 20 + b], h2n = gm2[(2 * HH + i) * 20 + b];
            float r2 = sigm(i2r + h2r);
            float z2 = sigm(i2z + h2z);
            float n2 = tanh_fast(i2n + r2 * h2n);
            float h = n2 + z2 * (h2prev[s] - n2);
            h2prev[s] = h;
            if (i < HH) {
                _Float16 hi = (_Float16)h;
                h2hi[b * 72 + i] = hi;
                h2lo[b * 72 + i] = (_Float16)(h - (float)hi);
            }
            p = fmaf(h, wlv[s], p);
        }
        p += __shfl_xor(p, 8);
        p += __shfl_xor(p, 16);
        p += __shfl_xor(p, 32);
        float out = p + blv;
        if (tid < BPB)
            storef(dout, (size_t)(blockIdx.x * BPB + tid) * TF + t, out, isbf);
        out_prev = out;
        __syncthreads();
    }
}

extern "C" void kernel_launch(void* const* d_in, const int* in_sizes, int n_in,
                              void* d_out, int out_size, void* d_ws, size_t ws_size,
                              hipStream_t stream) {
    const int B = 2048;
    const int T = in_sizes[0] / B;   // 1000
    const int TF = out_size / B;     // 2000
    gru_mfma_kernel<<<dim3(B / BPB), dim3(TPB), 0, stream>>>(
        d_in[0], d_in[1], d_in[2], d_in[3], d_in[4], d_in[5],
        d_in[6], d_in[7], d_in[8], d_in[9], d_in[10],
        d_out, T, TF);
}

// Round 4
// 3260.627 us; speedup vs baseline: 2.6988x; 2.6988x over previous
//
#include <hip/hip_runtime.h>
#include <hip/hip_bf16.h>

#define HH 51
#define TPB 512      // 8 waves
#define BPB 8        // batch per block
#define GMS 12       // gm leading stride (floats), 16B-aligned, conflict-friendly

typedef _Float16 half8 __attribute__((ext_vector_type(8)));
typedef float f4 __attribute__((ext_vector_type(4)));

__device__ __forceinline__ float bf2f(unsigned short u) {
    return __uint_as_float(((unsigned)u) << 16);
}
__device__ __forceinline__ float loadf(const void* p, size_t i, bool bf) {
    return bf ? bf2f(((const unsigned short*)p)[i]) : ((const float*)p)[i];
}
__device__ __forceinline__ void storef(void* p, size_t i, float v, bool bf) {
    if (bf) ((__hip_bfloat16*)p)[i] = __float2bfloat16(v);
    else    ((float*)p)[i] = v;
}
__device__ __forceinline__ float sigm(float v) {
    float e = __expf(-fabsf(v));
    float s = 1.0f / (1.0f + e);
    return (v >= 0.0f) ? s : 1.0f - s;
}
__device__ __forceinline__ float tanh_fast(float v) {
    float e = __expf(-2.0f * fabsf(v));
    float t = (1.0f - e) / (1.0f + e);
    return (v >= 0.0f) ? t : -t;
}
__device__ __forceinline__ f4 MF(half8 a, half8 b, f4 c) {
    return __builtin_amdgcn_mfma_f32_16x16x32_f16(a, b, c, 0, 0, 0);
}

// LDS map (bytes). Staging ws[3][160][64] f16 (61440) is a UNION with runtime:
//  gm1 @0 (7680) | gm2 @7680 (7680) | h1hi @15360 | h1lo @17664 | h2hi @19968
//  h2lo @22272 (each 16x72 f16 = 2304) | xbuf @24576 [2][8][64] f32 (4096)
//  obuf @28672 [2][8][64] f32 (4096) | wpart @32768 [8][8] f32 (256)
__global__ __launch_bounds__(TPB, 2) void gru_kernel(
    const void* __restrict__ xg,
    const void* __restrict__ wih1, const void* __restrict__ whh1,
    const void* __restrict__ bih1, const void* __restrict__ bhh1,
    const void* __restrict__ wih2, const void* __restrict__ whh2,
    const void* __restrict__ bih2, const void* __restrict__ bhh2,
    const void* __restrict__ wlin, const void* __restrict__ blin_p,
    void* __restrict__ dout, int T, int TF)
{
    __shared__ __align__(16) char L[61440];
    float*    gm1  = (float*)L;
    float*    gm2  = (float*)(L + 7680);
    _Float16* h1hi = (_Float16*)(L + 15360);
    _Float16* h1lo = (_Float16*)(L + 17664);
    _Float16* h2hi = (_Float16*)(L + 19968);
    _Float16* h2lo = (_Float16*)(L + 22272);
    float*    xbuf = (float*)(L + 24576);
    float*    obuf = (float*)(L + 28672);
    float*    wpart= (float*)(L + 32768);

    const int tid = threadIdx.x, w = tid >> 6, lane = tid & 63;
    const int n16 = lane & 15, quad = lane >> 4;
    const int eb = tid & 7, ei = tid >> 3;     // elementwise item (b, i)
    const bool eact = tid < 8 * HH;            // 408 items
    const int bg0 = blockIdx.x * BPB;

    // runtime dtype detection (fp32 vs bf16), uniform
    bool isbf;
    {
        const unsigned short* u = (const unsigned short*)whh1;
        int ok = 1;
#pragma unroll
        for (int k = 0; k < 16; ++k) {
            unsigned e = (u[2 * k] >> 7) & 0xFF;
            ok &= (e >= 100 && e <= 125) ? 1 : 0;
        }
        isbf = (ok != 0);
    }

    // ---- stage padded f16 weights into ws=L, bias folded at k=52 ----
    {
        _Float16* ws = (_Float16*)L;
        const void* wm[3] = { whh1, whh2, wih2 };
        for (int e = tid; e < 3 * 160 * 64; e += TPB) {
            int mt = e / 10240, r = e % 10240, g = r >> 6, k = r & 63;
            float v = 0.0f;
            if (g < 3 * HH) {
                if (k < HH) v = loadf(wm[mt], (size_t)g * HH + k, isbf);
                else if (k == 52) {
                    if (mt == 0)      v = loadf(bhh1, g, isbf) + ((g < 2 * HH) ? loadf(bih1, g, isbf) : 0.0f);
                    else if (mt == 1) v = loadf(bhh2, g, isbf);
                    else              v = loadf(bih2, g, isbf);
                }
            }
            ws[e] = (_Float16)v;
        }
    }
    __syncthreads();

    // ---- per-wave resident B fragments (static reg indexing, no spill) ----
    // phase A jobs j = w, w+8, w+16 (<20): j<10 -> Whh1 tile j ; else Whh2 tile j-10
    // phase B jobs j = w, w+8 (<10): Wih2 tile j
    half8 BA[3][2], BB[2][2];
    int tileA[3]; bool isM1[3]; const int nA = (w < 4) ? 3 : 2;
    int tileB[2];                const int nB = (w < 2) ? 2 : 1;
    {
        const _Float16* ws = (const _Float16*)L;
#pragma unroll
        for (int q = 0; q < 3; ++q) {
            int j = w + 8 * q;
            if (j < 20) {
                int mt = (j < 10) ? 0 : 1, tl = j % 10;
                tileA[q] = tl; isM1[q] = (j < 10);
                BA[q][0] = *(const half8*)(ws + ((size_t)(mt * 160 + 16 * tl + n16)) * 64 + quad * 8);
                BA[q][1] = *(const half8*)(ws + ((size_t)(mt * 160 + 16 * tl + n16)) * 64 + 32 + quad * 8);
            } else { tileA[q] = 0; isM1[q] = true; }
        }
#pragma unroll
        for (int q = 0; q < 2; ++q) {
            int j = w + 8 * q;
            if (j < 10) {
                tileB[q] = j;
                BB[q][0] = *(const half8*)(ws + ((size_t)(2 * 160 + 16 * j + n16)) * 64 + quad * 8);
                BB[q][1] = *(const half8*)(ws + ((size_t)(2 * 160 + 16 * j + n16)) * 64 + 32 + quad * 8);
            } else tileB[q] = 0;
        }
    }
    __syncthreads();   // frags snapshotted; staging region now reusable

    // ---- runtime buffer init ----
    for (int e = tid; e < 2304; e += TPB) ((unsigned*)(L + 15360))[e] = 0u; // h bufs
    if (tid < 64) wpart[tid] = 0.0f;
    {   // x chunk 0
        int b = tid >> 6, tt = tid & 63;
        float v = (tt < T) ? loadf(xg, (size_t)(bg0 + b) * T + tt, isbf) : 0.0f;
        xbuf[b * 64 + tt] = v;
    }
    __syncthreads();
    if (tid < BPB) { h1hi[tid * 72 + 52] = (_Float16)1.0f; h2hi[tid * 72 + 52] = (_Float16)1.0f; }

    float wr1 = 0, wz1 = 0, wn1 = 0, bn1 = 0, wl = 0;
    if (eact) {
        wr1 = loadf(wih1, ei, isbf);
        wz1 = loadf(wih1, HH + ei, isbf);
        wn1 = loadf(wih1, 2 * HH + ei, isbf);
        bn1 = loadf(bih1, 2 * HH + ei, isbf);
        wl  = loadf(wlin, ei, isbf);
    }
    const float blv = loadf(blin_p, 0, isbf);
    float h1p = 0.0f, h2p = 0.0f;
    __syncthreads();

    for (int t = 0; t < TF; ++t) {
        const int c = t >> 6, sl = t & 63;

        // out(t-1) finalize rides inside phase-A window (wave 0, lanes 0-7)
        if (tid < 8 && t > 0) {
            float s = 0.0f;
#pragma unroll
            for (int k = 0; k < 8; ++k) s += wpart[k * 8 + tid];
            obuf[(((t - 1) >> 6) & 1) * 512 + tid * 64 + ((t - 1) & 63)] = s + blv;
        }
        // ---- phase A: gh1 -> gm1, gh2 -> gm2 (split across waves) ----
        {
            const int m = n16;
            half8 x1a = *(const half8*)(h1hi + m * 72 + quad * 8);
            half8 x1b = *(const half8*)(h1hi + m * 72 + 32 + quad * 8);
            half8 y1a = *(const half8*)(h1lo + m * 72 + quad * 8);
            half8 y1b = *(const half8*)(h1lo + m * 72 + 32 + quad * 8);
            half8 x2a = *(const half8*)(h2hi + m * 72 + quad * 8);
            half8 x2b = *(const half8*)(h2hi + m * 72 + 32 + quad * 8);
            half8 y2a = *(const half8*)(h2lo + m * 72 + quad * 8);
            half8 y2b = *(const half8*)(h2lo + m * 72 + 32 + quad * 8);
#pragma unroll
            for (int q = 0; q < 3; ++q) {
                if (q >= nA) break;
                bool g1 = isM1[q]; int tl = tileA[q];
                f4 acc = {0.f, 0.f, 0.f, 0.f};
                acc = MF(g1 ? x1a : x2a, BA[q][0], acc);
                acc = MF(g1 ? x1b : x2b, BA[q][1], acc);
                acc = MF(g1 ? y1a : y2a, BA[q][0], acc);
                acc = MF(g1 ? y1b : y2b, BA[q][1], acc);
                if (quad < 2) *(f4*)((g1 ? gm1 : gm2) + (16 * tl + n16) * GMS + quad * 4) = acc;
            }
        }
        __syncthreads();

        // ---- chunk boundary: flush outputs, prefetch x (amortized 1/64) ----
        if (sl == 0) {
            if (t > 0) {
                int b = tid >> 6, tt = tid & 63;
                storef(dout, (size_t)(bg0 + b) * TF + (t - 64) + tt,
                       obuf[(((t >> 6) - 1) & 1) * 512 + b * 64 + tt], isbf);
            }
            int cn = c + 1;
            if (cn * 64 < T) {
                int b = tid >> 6, tt = tid & 63;
                int src = cn * 64 + tt;
                float v = (src < T) ? loadf(xg, (size_t)(bg0 + b) * T + src, isbf) : 0.0f;
                xbuf[(cn & 1) * 512 + b * 64 + tt] = v;
            }
        }

        // ---- elem1: layer-1 gates, h1 update (1 item/thread) ----
        if (eact) {
            float xv = (t < T) ? xbuf[(c & 1) * 512 + eb * 64 + sl]
                               : obuf[(((t - 1) >> 6) & 1) * 512 + eb * 64 + ((t - 1) & 63)];
            float hr = gm1[ei * GMS + eb];
            float hz = gm1[(HH + ei) * GMS + eb];
            float hn = gm1[(2 * HH + ei) * GMS + eb];
            float r = sigm(fmaf(xv, wr1, hr));
            float z = sigm(fmaf(xv, wz1, hz));
            float n = tanh_fast(fmaf(xv, wn1, bn1) + r * hn);
            float h = n + z * (h1p - n); h1p = h;
            _Float16 hi = (_Float16)h;
            h1hi[eb * 72 + ei] = hi;
            h1lo[eb * 72 + ei] = (_Float16)(h - (float)hi);
        }
        __syncthreads();

        // ---- phase B: gi2 = h1new . Wih2^T -> gm1 ----
        {
            const int m = n16;
            half8 x1a = *(const half8*)(h1hi + m * 72 + quad * 8);
            half8 x1b = *(const half8*)(h1hi + m * 72 + 32 + quad * 8);
            half8 y1a = *(const half8*)(h1lo + m * 72 + quad * 8);
            half8 y1b = *(const half8*)(h1lo + m * 72 + 32 + quad * 8);
#pragma unroll
            for (int q = 0; q < 2; ++q) {
                if (q >= nB) break;
                int tl = tileB[q];
                f4 acc = {0.f, 0.f, 0.f, 0.f};
                acc = MF(x1a, BB[q][0], acc);
                acc = MF(x1b, BB[q][1], acc);
                acc = MF(y1a, BB[q][0], acc);
                acc = MF(y1b, BB[q][1], acc);
                if (quad < 2) *(f4*)(gm1 + (16 * tl + n16) * GMS + quad * 4) = acc;
            }
        }
        __syncthreads();

        // ---- elem2: layer-2 gates, h2 update, output partials ----
        float p = 0.0f;
        if (eact) {
            float ir = gm1[ei * GMS + eb], iz = gm1[(HH + ei) * GMS + eb], nn = gm1[(2 * HH + ei) * GMS + eb];
            float hr = gm2[ei * GMS + eb], hz = gm2[(HH + ei) * GMS + eb], hn = gm2[(2 * HH + ei) * GMS + eb];
            float r = sigm(ir + hr);
            float z = sigm(iz + hz);
            float n = tanh_fast(nn + r * hn);
            float h = n + z * (h2p - n); h2p = h;
            _Float16 hi = (_Float16)h;
            h2hi[eb * 72 + ei] = hi;
            h2lo[eb * 72 + ei] = (_Float16)(h - (float)hi);
            p = h * wl;
        }
        p += __shfl_xor(p, 8);
        p += __shfl_xor(p, 16);
        p += __shfl_xor(p, 32);
        if (lane < 8) wpart[w * 8 + lane] = p;
        __syncthreads();
    }

    // ---- tail: finalize out(TF-1), flush last partial chunk ----
    if (tid < 8) {
        float s = 0.0f;
#pragma unroll
        for (int k = 0; k < 8; ++k) s += wpart[k * 8 + tid];
        obuf[(((TF - 1) >> 6) & 1) * 512 + tid * 64 + ((TF - 1) & 63)] = s + blv;
    }
    __syncthreads();
    {
        int lastF = ((TF - 1) >> 6) << 6, rem = TF - lastF;
        for (int e = tid; e < BPB * rem; e += TPB) {
            int b = e / rem, tt = e % rem;
            storef(dout, (size_t)(bg0 + b) * TF + lastF + tt,
                   obuf[((lastF >> 6) & 1) * 512 + b * 64 + tt], isbf);
        }
    }
}

extern "C" void kernel_launch(void* const* d_in, const int* in_sizes, int n_in,
                              void* d_out, int out_size, void* d_ws, size_t ws_size,
                              hipStream_t stream) {
    const int B = 2048;
    const int T = in_sizes[0] / B;   // 1000
    const int TF = out_size / B;     // 2000
    gru_kernel<<<dim3(B / BPB), dim3(TPB), 0, stream>>>(
        d_in[0], d_in[1], d_in[2], d_in[3], d_in[4], d_in[5],
        d_in[6], d_in[7], d_in[8], d_in[9], d_in[10],
        d_out, T, TF);
}

// Round 5
// 2811.818 us; speedup vs baseline: 3.1296x; 1.1596x over previous
//
#include <hip/hip_runtime.h>
#include <hip/hip_bf16.h>

#define HH 51
#define TPB 512      // 8 waves: 0-2 matmul-spec, 3-7 elementwise-spec
#define BPB 8        // batch per block
#define GMS 12       // gm leading stride (floats)

typedef _Float16 half8 __attribute__((ext_vector_type(8)));
typedef float f4 __attribute__((ext_vector_type(4)));

__device__ __forceinline__ float bf2f(unsigned short u) {
    return __uint_as_float(((unsigned)u) << 16);
}
__device__ __forceinline__ float loadf(const void* p, size_t i, bool bf) {
    return bf ? bf2f(((const unsigned short*)p)[i]) : ((const float*)p)[i];
}
__device__ __forceinline__ void storef(void* p, size_t i, float v, bool bf) {
    if (bf) ((__hip_bfloat16*)p)[i] = __float2bfloat16(v);
    else    ((float*)p)[i] = v;
}
__device__ __forceinline__ float sigm(float v) {
    float e = __expf(-fabsf(v));
    float s = 1.0f / (1.0f + e);
    return (v >= 0.0f) ? s : 1.0f - s;
}
__device__ __forceinline__ float tanh_fast(float v) {
    float e = __expf(-2.0f * fabsf(v));
    float t = (1.0f - e) / (1.0f + e);
    return (v >= 0.0f) ? t : -t;
}
__device__ __forceinline__ f4 MF(half8 a, half8 b, f4 c) {
    return __builtin_amdgcn_mfma_f32_16x16x32_f16(a, b, c, 0, 0, 0);
}

// LDS map (bytes), runtime layout UNIONed with 61440B staging ws[3][160][64] f16:
//  gmA(gh1)@0  gmB(gh2)@7680  gmC(gi2)@15360   (160*12*4 = 7680 each)
//  h1hi@23040 h1lo@25344 h2hi@27648 h2lo@29952 (16*72*2 = 2304 each)
//  xbuf@32256 [2][8][68] f32 (4352) | obuf@36608 [2][8][68] (4352) | xacc@40960 [2][8]
__global__ __launch_bounds__(TPB, 2) void gru_kernel(
    const void* __restrict__ xg,
    const void* __restrict__ wih1, const void* __restrict__ whh1,
    const void* __restrict__ bih1, const void* __restrict__ bhh1,
    const void* __restrict__ wih2, const void* __restrict__ whh2,
    const void* __restrict__ bih2, const void* __restrict__ bhh2,
    const void* __restrict__ wlin, const void* __restrict__ blin_p,
    void* __restrict__ dout, int T, int TF)
{
    __shared__ __align__(16) char L[61440];
    float*    gmA  = (float*)L;
    float*    gmB  = (float*)(L + 7680);
    float*    gmC  = (float*)(L + 15360);
    _Float16* h1hi = (_Float16*)(L + 23040);
    _Float16* h1lo = (_Float16*)(L + 25344);
    _Float16* h2hi = (_Float16*)(L + 27648);
    _Float16* h2lo = (_Float16*)(L + 29952);
    float*    xbuf = (float*)(L + 32256);
    float*    obuf = (float*)(L + 36608);
    float*    xacc = (float*)(L + 40960);

    const int tid = threadIdx.x, w = tid >> 6, lane = tid & 63;
    const int n16 = lane & 15, quad = lane >> 4;
    const int bg0 = blockIdx.x * BPB;
    const bool mmw = (w < 3);
    // elementwise ids (waves 3-7): item1 = eix (i<40), item2 = eix+320 (i+40)
    const int eix = (w - 3) * 64 + lane;
    const int eb  = lane & 7;
    const int ei  = eix >> 3;
    const bool sec = (!mmw) && (eix < 88);

    // ---- runtime dtype detection (fp32 vs bf16), uniform ----
    bool isbf;
    {
        const unsigned short* u = (const unsigned short*)whh1;
        int ok = 1;
#pragma unroll
        for (int k = 0; k < 16; ++k) {
            unsigned e = (u[2 * k] >> 7) & 0xFF;
            ok &= (e >= 100 && e <= 125) ? 1 : 0;
        }
        isbf = (ok != 0);
    }

    // ---- stage padded f16 weights into ws=L, bias folded at k=52 ----
    {
        _Float16* ws = (_Float16*)L;
        const void* wm[3] = { whh1, whh2, wih2 };
        for (int e = tid; e < 3 * 160 * 64; e += TPB) {
            int mt = e / 10240, r = e % 10240, g = r >> 6, k = r & 63;
            float v = 0.0f;
            if (g < 3 * HH) {
                if (k < HH) v = loadf(wm[mt], (size_t)g * HH + k, isbf);
                else if (k == 52) {
                    if (mt == 0)      v = loadf(bhh1, g, isbf) + ((g < 2 * HH) ? loadf(bih1, g, isbf) : 0.0f);
                    else if (mt == 1) v = loadf(bhh2, g, isbf);
                    else              v = loadf(bih2, g, isbf);
                }
            }
            ws[e] = (_Float16)v;
        }
    }
    __syncthreads();

    // ---- resident B fragments ----
    // mm waves (w<3): FA = Whh2 tiles {w,w+3,w+6,w+9}, FC = Whh1 same tiles
    // all waves: FB[0] = Wih2 tile w ; FB[1] = Wih2 tile w+8 (w<2)
    half8 FA[4][2], FC[4][2], FB[2][2];
    {
        const _Float16* ws = (const _Float16*)L;
        if (mmw) {
#pragma unroll
            for (int q = 0; q < 4; ++q) {
                int tl = w + 3 * q;
                if (tl < 10) {
                    FA[q][0] = *(const half8*)(ws + ((size_t)(160 + 16 * tl + n16)) * 64 + quad * 8);
                    FA[q][1] = *(const half8*)(ws + ((size_t)(160 + 16 * tl + n16)) * 64 + 32 + quad * 8);
                    FC[q][0] = *(const half8*)(ws + ((size_t)(16 * tl + n16)) * 64 + quad * 8);
                    FC[q][1] = *(const half8*)(ws + ((size_t)(16 * tl + n16)) * 64 + 32 + quad * 8);
                }
            }
        }
        FB[0][0] = *(const half8*)(ws + ((size_t)(320 + 16 * w + n16)) * 64 + quad * 8);
        FB[0][1] = *(const half8*)(ws + ((size_t)(320 + 16 * w + n16)) * 64 + 32 + quad * 8);
        if (w < 2) {
            FB[1][0] = *(const half8*)(ws + ((size_t)(320 + 16 * (w + 8) + n16)) * 64 + quad * 8);
            FB[1][1] = *(const half8*)(ws + ((size_t)(320 + 16 * (w + 8) + n16)) * 64 + 32 + quad * 8);
        }
    }
    __syncthreads();   // frags snapshotted; staging region reusable

    // ---- runtime buffer init ----
    for (int e = tid; e < 2304; e += TPB) ((unsigned*)(L + 23040))[e] = 0u;  // h bufs
    if (tid < 16) xacc[tid] = 0.0f;
    {   // x chunk 0
        int b = tid >> 6, tt = tid & 63;
        xbuf[b * 68 + tt] = (tt < T) ? loadf(xg, (size_t)(bg0 + b) * T + tt, isbf) : 0.0f;
    }
    // elem constants
    float wr1a = 0, wz1a = 0, wn1a = 0, bn1a = 0, wla = 0;
    float wr1b = 0, wz1b = 0, wn1b = 0, bn1b = 0, wlb = 0;
    if (!mmw) {
        wr1a = loadf(wih1, ei, isbf);      wz1a = loadf(wih1, HH + ei, isbf);
        wn1a = loadf(wih1, 2 * HH + ei, isbf); bn1a = loadf(bih1, 2 * HH + ei, isbf);
        wla  = loadf(wlin, ei, isbf);
        if (sec) {
            int i2 = ei + 40;
            wr1b = loadf(wih1, i2, isbf);      wz1b = loadf(wih1, HH + i2, isbf);
            wn1b = loadf(wih1, 2 * HH + i2, isbf); bn1b = loadf(bih1, 2 * HH + i2, isbf);
            wlb  = loadf(wlin, i2, isbf);
        }
    }
    const float blv = loadf(blin_p, 0, isbf);
    __syncthreads();
    if (tid < BPB) { h1hi[tid * 72 + 52] = (_Float16)1.0f; h2hi[tid * 72 + 52] = (_Float16)1.0f; }
    __syncthreads();

    // ---- prologue: gmA = gh1(0) from initial h1 (bias slot) ----
    if (mmw) {
        half8 a0 = *(const half8*)(h1hi + n16 * 72 + quad * 8);
        half8 a1 = *(const half8*)(h1hi + n16 * 72 + 32 + quad * 8);
        half8 a2 = *(const half8*)(h1lo + n16 * 72 + quad * 8);
        half8 a3 = *(const half8*)(h1lo + n16 * 72 + 32 + quad * 8);
#pragma unroll
        for (int q = 0; q < 4; ++q) {
            int tl = w + 3 * q;
            if (tl < 10) {
                f4 acc = {0.f, 0.f, 0.f, 0.f};
                acc = MF(a0, FC[q][0], acc); acc = MF(a1, FC[q][1], acc);
                acc = MF(a2, FC[q][0], acc); acc = MF(a3, FC[q][1], acc);
                if (quad < 2) *(f4*)(gmA + (16 * tl + n16) * GMS + quad * 4) = acc;
            }
        }
    }
    __syncthreads();

    float h1pa = 0, h1pb = 0, h2pa = 0, h2pb = 0;

    for (int t = 0; t < TF; ++t) {
        const int c = t >> 6, sl = t & 63, sc = t & 1, sp = sc ^ 1;

        // ======== P1: mm waves gh2(t) -> gmB ; e waves e1 ========
        if (mmw) {
            if (tid < 8 && t > 0)
                obuf[(((t - 1) >> 6) & 1) * 544 + tid * 68 + ((t - 1) & 63)] = xacc[sp * 8 + tid] + blv;
            if (tid >= 8 && tid < 16) xacc[sc * 8 + (tid - 8)] = 0.0f;
            half8 a0 = *(const half8*)(h2hi + n16 * 72 + quad * 8);
            half8 a1 = *(const half8*)(h2hi + n16 * 72 + 32 + quad * 8);
            half8 a2 = *(const half8*)(h2lo + n16 * 72 + quad * 8);
            half8 a3 = *(const half8*)(h2lo + n16 * 72 + 32 + quad * 8);
#pragma unroll
            for (int q = 0; q < 4; ++q) {
                int tl = w + 3 * q;
                if (tl < 10) {
                    f4 acc = {0.f, 0.f, 0.f, 0.f};
                    acc = MF(a0, FA[q][0], acc); acc = MF(a1, FA[q][1], acc);
                    acc = MF(a2, FA[q][0], acc); acc = MF(a3, FA[q][1], acc);
                    if (quad < 2) *(f4*)(gmB + (16 * tl + n16) * GMS + quad * 4) = acc;
                }
            }
        } else {
            float xv = (t < T) ? xbuf[(c & 1) * 544 + eb * 68 + sl]
                               : (xacc[sp * 8 + eb] + blv);
            {
                float hr = gmA[ei * GMS + eb];
                float hz = gmA[(HH + ei) * GMS + eb];
                float hn = gmA[(2 * HH + ei) * GMS + eb];
                float r = sigm(fmaf(xv, wr1a, hr));
                float z = sigm(fmaf(xv, wz1a, hz));
                float n = tanh_fast(fmaf(xv, wn1a, bn1a) + r * hn);
                float h = n + z * (h1pa - n); h1pa = h;
                _Float16 hi = (_Float16)h;
                h1hi[eb * 72 + ei] = hi;
                h1lo[eb * 72 + ei] = (_Float16)(h - (float)hi);
            }
            if (sec) {
                int i2 = ei + 40;
                float hr = gmA[i2 * GMS + eb];
                float hz = gmA[(HH + i2) * GMS + eb];
                float hn = gmA[(2 * HH + i2) * GMS + eb];
                float r = sigm(fmaf(xv, wr1b, hr));
                float z = sigm(fmaf(xv, wz1b, hz));
                float n = tanh_fast(fmaf(xv, wn1b, bn1b) + r * hn);
                float h = n + z * (h1pb - n); h1pb = h;
                _Float16 hi = (_Float16)h;
                h1hi[eb * 72 + i2] = hi;
                h1lo[eb * 72 + i2] = (_Float16)(h - (float)hi);
            }
        }
        __syncthreads();

        // ======== P2: all waves gi2(t) -> gmC ; amortized chunk I/O ========
        if (sl == 0) {
            int b = tid >> 6, tt = tid & 63;
            if (t > 0)
                storef(dout, (size_t)(bg0 + b) * TF + (t - 64) + tt,
                       obuf[((c - 1) & 1) * 544 + b * 68 + tt], isbf);
            int cn = c + 1;
            if (cn * 64 < T) {
                int src = cn * 64 + tt;
                xbuf[(cn & 1) * 544 + b * 68 + tt] =
                    (src < T) ? loadf(xg, (size_t)(bg0 + b) * T + src, isbf) : 0.0f;
            }
        }
        {
            half8 a0 = *(const half8*)(h1hi + n16 * 72 + quad * 8);
            half8 a1 = *(const half8*)(h1hi + n16 * 72 + 32 + quad * 8);
            half8 a2 = *(const half8*)(h1lo + n16 * 72 + quad * 8);
            half8 a3 = *(const half8*)(h1lo + n16 * 72 + 32 + quad * 8);
            {
                f4 acc = {0.f, 0.f, 0.f, 0.f};
                acc = MF(a0, FB[0][0], acc); acc = MF(a1, FB[0][1], acc);
                acc = MF(a2, FB[0][0], acc); acc = MF(a3, FB[0][1], acc);
                if (quad < 2) *(f4*)(gmC + (16 * w + n16) * GMS + quad * 4) = acc;
            }
            if (w < 2) {
                f4 acc = {0.f, 0.f, 0.f, 0.f};
                acc = MF(a0, FB[1][0], acc); acc = MF(a1, FB[1][1], acc);
                acc = MF(a2, FB[1][0], acc); acc = MF(a3, FB[1][1], acc);
                if (quad < 2) *(f4*)(gmC + (16 * (w + 8) + n16) * GMS + quad * 4) = acc;
            }
        }
        __syncthreads();

        // ======== P3: mm waves gh1(t+1) -> gmA ; e waves e2 + reduce ========
        if (mmw) {
            half8 a0 = *(const half8*)(h1hi + n16 * 72 + quad * 8);
            half8 a1 = *(const half8*)(h1hi + n16 * 72 + 32 + quad * 8);
            half8 a2 = *(const half8*)(h1lo + n16 * 72 + quad * 8);
            half8 a3 = *(const half8*)(h1lo + n16 * 72 + 32 + quad * 8);
#pragma unroll
            for (int q = 0; q < 4; ++q) {
                int tl = w + 3 * q;
                if (tl < 10) {
                    f4 acc = {0.f, 0.f, 0.f, 0.f};
                    acc = MF(a0, FC[q][0], acc); acc = MF(a1, FC[q][1], acc);
                    acc = MF(a2, FC[q][0], acc); acc = MF(a3, FC[q][1], acc);
                    if (quad < 2) *(f4*)(gmA + (16 * tl + n16) * GMS + quad * 4) = acc;
                }
            }
        } else {
            float p = 0.0f;
            {
                float ir = gmC[ei * GMS + eb], iz = gmC[(HH + ei) * GMS + eb], inn = gmC[(2 * HH + ei) * GMS + eb];
                float hr = gmB[ei * GMS + eb], hz = gmB[(HH + ei) * GMS + eb], hn = gmB[(2 * HH + ei) * GMS + eb];
                float r = sigm(ir + hr);
                float z = sigm(iz + hz);
                float n = tanh_fast(inn + r * hn);
                float h = n + z * (h2pa - n); h2pa = h;
                _Float16 hi = (_Float16)h;
                h2hi[eb * 72 + ei] = hi;
                h2lo[eb * 72 + ei] = (_Float16)(h - (float)hi);
                p = fmaf(h, wla, p);
            }
            if (sec) {
                int i2 = ei + 40;
                float ir = gmC[i2 * GMS + eb], iz = gmC[(HH + i2) * GMS + eb], inn = gmC[(2 * HH + i2) * GMS + eb];
                float hr = gmB[i2 * GMS + eb], hz = gmB[(HH + i2) * GMS + eb], hn = gmB[(2 * HH + i2) * GMS + eb];
                float r = sigm(ir + hr);
                float z = sigm(iz + hz);
                float n = tanh_fast(inn + r * hn);
                float h = n + z * (h2pb - n); h2pb = h;
                _Float16 hi = (_Float16)h;
                h2hi[eb * 72 + i2] = hi;
                h2lo[eb * 72 + i2] = (_Float16)(h - (float)hi);
                p = fmaf(h, wlb, p);
            }
            p += __shfl_xor(p, 8);
            p += __shfl_xor(p, 16);
            p += __shfl_xor(p, 32);
            if (lane < 8) atomicAdd(&xacc[sc * 8 + lane], p);
        }
        __syncthreads();
    }

    // ---- tail: finalize out(TF-1), flush remainder ----
    if (tid < 8)
        obuf[(((TF - 1) >> 6) & 1) * 544 + tid * 68 + ((TF - 1) & 63)] =
            xacc[((TF - 1) & 1) * 8 + tid] + blv;
    __syncthreads();
    {
        int lastF = (TF - 1) & ~63, rem = TF - lastF;
        for (int e = tid; e < BPB * rem; e += TPB) {
            int b = e / rem, tt = e % rem;
            storef(dout, (size_t)(bg0 + b) * TF + lastF + tt,
                   obuf[((lastF >> 6) & 1) * 544 + b * 68 + tt], isbf);
        }
    }
}

extern "C" void kernel_launch(void* const* d_in, const int* in_sizes, int n_in,
                              void* d_out, int out_size, void* d_ws, size_t ws_size,
                              hipStream_t stream) {
    const int B = 2048;
    const int T = in_sizes[0] / B;   // 1000
    const int TF = out_size / B;     // 2000
    gru_kernel<<<dim3(B / BPB), dim3(TPB), 0, stream>>>(
        d_in[0], d_in[1], d_in[2], d_in[3], d_in[4], d_in[5],
        d_in[6], d_in[7], d_in[8], d_in[9], d_in[10],
        d_out, T, TF);
}